// Round 9
// baseline (519.303 us; speedup 1.0000x reference)
//
#include <hip/hip_runtime.h>

#define D 64
#define ALPHA 0.01f
#define EPS 1e-5f
#define NREP 8            // stats replica buffers
#define CAP 48            // bucket capacity; P(Poisson(12) >= 48) ~ 3e-15 per node
#define GSZ 128           // nodes per group (group = col >> 7)
#define GMAX 1024         // max groups supported (n <= 131072)
#define NB 256            // blocks for binA / binB

typedef __attribute__((ext_vector_type(8))) short short8;   // 8 bf16 = 4 VGPRs
typedef __attribute__((ext_vector_type(4))) float f32x4;

__device__ inline unsigned short f2bf(float f) {            // round-to-nearest-even
    unsigned u = __float_as_uint(f);
    u += 0x7fffu + ((u >> 16) & 1u);
    return (unsigned short)(u >> 16);
}
__device__ inline float bf2f(unsigned short h) { return __uint_as_float((unsigned)h << 16); }

// ---------------- prep: x->bf16, stats = 0 ----------------
__global__ void k_prep(const float4* __restrict__ x4, ushort4* __restrict__ xb4,
                       float* __restrict__ stats, long long n16) {
    long long i = (long long)blockIdx.x * blockDim.x + threadIdx.x;
    if (i < n16) {
        float4 v = x4[i];
        ushort4 r;
        r.x = f2bf(v.x); r.y = f2bf(v.y); r.z = f2bf(v.z); r.w = f2bf(v.w);
        xb4[i] = r;
    }
    if (i < NREP * 128) stats[i] = 0.0f;
}

// ---------------- binA: per-block LDS histogram over node-groups ----------------
__global__ __launch_bounds__(256) void k_binA(const int* __restrict__ col,
                                              int* __restrict__ cnt_gb, int G, int E) {
    __shared__ int h[GMAX];
    int b = blockIdx.x;
    for (int i = threadIdx.x; i < G; i += 256) h[i] = 0;
    __syncthreads();
    int chunk = (E + NB - 1) / NB;
    int e0 = b * chunk;
    int e1 = e0 + chunk; if (e1 > E) e1 = E;
    for (int e = e0 + threadIdx.x; e < e1; e += 256)
        atomicAdd(&h[col[e] >> 7], 1);
    __syncthreads();
    for (int i = threadIdx.x; i < G; i += 256)
        cnt_gb[i * NB + b] = h[i];          // [g][b] layout (group-major flat)
}

// ---------------- scan: global exclusive scan of (g,b) counts, coalesced ----------------
// pos[f] = absolute start slot of (g = f>>8, b = f&255); gseg[g] = segment start; gseg[G] = E
__global__ __launch_bounds__(256) void k_scan(const int* __restrict__ cnt_gb,
                                              int* __restrict__ pos,
                                              int* __restrict__ gseg, int G, int E) {
    __shared__ int ps[256];
    int t = threadIdx.x;
    int base = t * G;                       // thread range [base, base+G), total G*256
    int s = 0;
    for (int i = 0; i < G; ++i) s += cnt_gb[base + i];
    ps[t] = s;
    __syncthreads();
    int own = s;
    for (int off = 1; off < 256; off <<= 1) {
        int v = (t >= off) ? ps[t - off] : 0;
        __syncthreads();
        ps[t] += v;
        __syncthreads();
    }
    int run = ps[t] - own;                  // exclusive
    for (int i = 0; i < G; ++i) {
        int f = base + i;
        pos[f] = run;
        if ((f & (NB - 1)) == 0) gseg[f >> 8] = run;
        run += cnt_gb[f];
    }
    if (t == 0) gseg[G] = E;
}

// ---------------- binB: scatter edges into group segments (LDS cursors, no global atomics) ----
// entry: x = (wq 15b << 17) | row 17b  (== final bucket entry); y = col within group (7b)
__global__ __launch_bounds__(256) void k_binB(const int* __restrict__ eidx,
                                              const float* __restrict__ w,
                                              const int* __restrict__ pos,
                                              uint2* __restrict__ seg, int G, int E) {
    __shared__ int cursor[GMAX];
    int b = blockIdx.x;
    for (int g = threadIdx.x; g < G; g += 256) cursor[g] = pos[g * NB + b];
    __syncthreads();
    int chunk = (E + NB - 1) / NB;
    int e0 = b * chunk;
    int e1 = e0 + chunk; if (e1 > E) e1 = E;
    for (int e = e0 + threadIdx.x; e < e1; e += 256) {
        int row = eidx[e];
        int c = eidx[E + e];
        unsigned wq = (unsigned)(w[e] * 32767.0f + 0.5f);
        int slot = atomicAdd(&cursor[c >> 7], 1);
        seg[slot] = make_uint2((wq << 17) | (unsigned)row, (unsigned)(c & (GSZ - 1)));
    }
}

// ---------------- binC: per-group ranks (LDS) -> bucket, cnt, dis ----------------
__global__ __launch_bounds__(256) void k_binC(const uint2* __restrict__ seg,
                                              const int* __restrict__ gseg,
                                              unsigned* __restrict__ bucket,
                                              int* __restrict__ cnt,
                                              float* __restrict__ dis, int n) {
    __shared__ int cl[GSZ];
    __shared__ float ws[GSZ];
    int g = blockIdx.x;
    if (threadIdx.x < GSZ) { cl[threadIdx.x] = 0; ws[threadIdx.x] = 0.0f; }
    __syncthreads();
    int s0 = gseg[g], s1 = gseg[g + 1];
    for (int i = s0 + threadIdx.x; i < s1; i += 256) {
        uint2 ev = seg[i];
        int cig = (int)ev.y;
        int rank = atomicAdd(&cl[cig], 1);
        atomicAdd(&ws[cig], (float)(ev.x >> 17) * (1.0f / 32767.0f));
        int node = g * GSZ + cig;
        if (rank < CAP) bucket[(size_t)node * CAP + rank] = ev.x;
    }
    __syncthreads();
    if (threadIdx.x < GSZ) {
        int node = g * GSZ + threadIdx.x;
        if (node < n) {
            cnt[node] = cl[threadIdx.x];
            dis[node] = rsqrtf(1.0f + ws[threadIdx.x]);   // self-loop weight 1
        }
    }
}

// ---------------- gather: agg = A * x (one wave/node: 8 edge-slots x 8 lanes x 16B bf16) ----------------
__global__ __launch_bounds__(256) void k_gather(const unsigned short* __restrict__ xb,
                                                const unsigned* __restrict__ bucket,
                                                const int* __restrict__ cnt,
                                                const float* __restrict__ dis,
                                                unsigned short* __restrict__ aggb, int n) {
    int node = blockIdx.x * 4 + (threadIdx.x >> 6);
    if (node >= n) return;
    int lane = threadIdx.x & 63;
    int g = lane >> 3;      // edge slot 0..7
    int l = lane & 7;       // feature group (features 8l..8l+7)
    int c = cnt[node];
    if (c > CAP) c = CAP;
    float di = dis[node];
    float acc[8] = {0, 0, 0, 0, 0, 0, 0, 0};
    if (g == 0) {           // self-loop: norm = dis^2 = 1/deg
        float sl = di * di;
        short8 xv = *(const short8*)(xb + (size_t)node * 64 + l * 8);
#pragma unroll
        for (int k = 0; k < 8; ++k) acc[k] = bf2f((unsigned short)xv[k]) * sl;
    }
    for (int j = g; j < c; j += 8) {
        unsigned v = bucket[(size_t)node * CAP + j];
        int src = (int)(v & 0x1FFFFu);
        float we = (float)(v >> 17) * (1.0f / 32767.0f);
        float nrm = we * dis[src] * di;
        short8 xv = *(const short8*)(xb + (size_t)src * 64 + l * 8);
#pragma unroll
        for (int k = 0; k < 8; ++k) acc[k] += nrm * bf2f((unsigned short)xv[k]);
    }
#pragma unroll
    for (int off = 8; off <= 32; off <<= 1)
#pragma unroll
        for (int k = 0; k < 8; ++k) acc[k] += __shfl_xor(acc[k], off, 64);
    if (g == 0) {
        short8 r;
#pragma unroll
        for (int k = 0; k < 8; ++k) r[k] = (short)f2bf(acc[k]);
        *(short8*)(aggb + (size_t)node * 64 + l * 8) = r;
    }
}

// ---------------- out = agg @ W via MFMA 16x16x32 bf16, fused BN-stats ----------------
__global__ __launch_bounds__(256) void k_gemmstats(const unsigned short* __restrict__ aggb,
                                                   const float* __restrict__ Wm,
                                                   float* __restrict__ out,
                                                   float* __restrict__ stats, int n) {
    __shared__ unsigned short Wt[64 * 64];   // 8 KB, Wt[nn*64 + k]
    __shared__ float ssum[4][64], qsum[4][64];
    int tid = threadIdx.x;
    for (int i = tid; i < 4096; i += 256) {
        int k = i >> 6, nn = i & 63;
        Wt[nn * 64 + k] = f2bf(Wm[i]);
    }
    __syncthreads();
    int wv = tid >> 6;
    int lane = tid & 63;
    int l15 = lane & 15;
    int quad = lane >> 4;

    short8 bfrag[2][4];
#pragma unroll
    for (int h = 0; h < 2; ++h)
#pragma unroll
        for (int g = 0; g < 4; ++g)
            bfrag[h][g] = *(const short8*)&Wt[(g * 16 + l15) * 64 + h * 32 + quad * 8];

    float s[4] = {0, 0, 0, 0}, q[4] = {0, 0, 0, 0};
    int nwt = (n + 15) >> 4;   // wave-tiles
    for (int wt = blockIdx.x * 4 + wv; wt < nwt; wt += gridDim.x * 4) {
        int row0 = wt * 16;
        int arow = row0 + l15;
        if (arow >= n) arow = n - 1;           // clamp: loads stay in-bounds
        const unsigned short* ap = aggb + (size_t)arow * 64 + quad * 8;
        short8 a0 = *(const short8*)ap;
        short8 a1 = *(const short8*)(ap + 32);
        f32x4 acc[4] = {{0, 0, 0, 0}, {0, 0, 0, 0}, {0, 0, 0, 0}, {0, 0, 0, 0}};
#pragma unroll
        for (int g = 0; g < 4; ++g) {
            acc[g] = __builtin_amdgcn_mfma_f32_16x16x32_bf16(a0, bfrag[0][g], acc[g], 0, 0, 0);
            acc[g] = __builtin_amdgcn_mfma_f32_16x16x32_bf16(a1, bfrag[1][g], acc[g], 0, 0, 0);
        }
#pragma unroll
        for (int r = 0; r < 4; ++r) {
            int row = row0 + quad * 4 + r;
            if (row < n) {
                size_t base = (size_t)row * 64;
#pragma unroll
                for (int g = 0; g < 4; ++g) {
                    float v = acc[g][r];
                    out[base + g * 16 + l15] = v;
                    s[g] += v;
                    q[g] += v * v;
                }
            }
        }
    }
#pragma unroll
    for (int off = 16; off <= 32; off <<= 1) {
#pragma unroll
        for (int g = 0; g < 4; ++g) {
            s[g] += __shfl_xor(s[g], off, 64);
            q[g] += __shfl_xor(q[g], off, 64);
        }
    }
    if (quad == 0) {
#pragma unroll
        for (int g = 0; g < 4; ++g) { ssum[wv][g * 16 + l15] = s[g]; qsum[wv][g * 16 + l15] = q[g]; }
    }
    __syncthreads();
    float* st = stats + (blockIdx.x & (NREP - 1)) * 128;
    if (tid < 64)
        atomicAdd(&st[tid], ssum[0][tid] + ssum[1][tid] + ssum[2][tid] + ssum[3][tid]);
    else if (tid < 128) {
        int t = tid - 64;
        atomicAdd(&st[64 + t], qsum[0][t] + qsum[1][t] + qsum[2][t] + qsum[3][t]);
    }
}

// ---------------- batchnorm + leakyrelu, in place, float4 ----------------
__global__ __launch_bounds__(256) void k_norm(float4* __restrict__ out4,
                                              const float* __restrict__ stats,
                                              const float* __restrict__ gamma,
                                              const float* __restrict__ beta, int n) {
    __shared__ float scale[64], shift[64];
    if (threadIdx.x < 64) {
        float sm = 0.0f, qm = 0.0f;
#pragma unroll
        for (int r = 0; r < NREP; ++r) {
            sm += stats[r * 128 + threadIdx.x];
            qm += stats[r * 128 + 64 + threadIdx.x];
        }
        float inv_n = 1.0f / (float)n;
        float mean = sm * inv_n;
        float var = qm * inv_n - mean * mean;
        float sc = rsqrtf(var + EPS) * gamma[threadIdx.x];
        scale[threadIdx.x] = sc;
        shift[threadIdx.x] = beta[threadIdx.x] - mean * sc;
    }
    __syncthreads();
    long long idx = (long long)blockIdx.x * blockDim.x + threadIdx.x;
    if (idx < (long long)n * 16) {
        int l = (int)(idx & 15);
        float4 v = out4[idx];
        float4 r;
        float a, b2;
        a = scale[l * 4 + 0]; b2 = shift[l * 4 + 0]; r.x = v.x * a + b2; r.x = r.x >= 0.0f ? r.x : ALPHA * r.x;
        a = scale[l * 4 + 1]; b2 = shift[l * 4 + 1]; r.y = v.y * a + b2; r.y = r.y >= 0.0f ? r.y : ALPHA * r.y;
        a = scale[l * 4 + 2]; b2 = shift[l * 4 + 2]; r.z = v.z * a + b2; r.z = r.z >= 0.0f ? r.z : ALPHA * r.z;
        a = scale[l * 4 + 3]; b2 = shift[l * 4 + 3]; r.w = v.w * a + b2; r.w = r.w >= 0.0f ? r.w : ALPHA * r.w;
        out4[idx] = r;
    }
}

extern "C" void kernel_launch(void* const* d_in, const int* in_sizes, int n_in,
                              void* d_out, int out_size, void* d_ws, size_t ws_size,
                              hipStream_t stream) {
    const float* x     = (const float*)d_in[0];
    const int*   eidx  = (const int*)d_in[1];
    const float* eattr = (const float*)d_in[2];
    const float* Wm    = (const float*)d_in[3];
    // d_in[4] = b : constant per-feature shift, cancels exactly in BatchNorm — skipped
    const float* gamma = (const float*)d_in[5];
    const float* beta  = (const float*)d_in[6];
    float* out = (float*)d_out;

    int n = in_sizes[0] / D;      // 100000 < 2^17 (17-bit src packing, GMAX groups)
    int E = in_sizes[2];
    int G = (n + GSZ - 1) / GSZ;  // 782 node-groups

    // workspace layout (all sections 16B-aligned for n=100000, E=1.2M)
    char* p = (char*)d_ws;
    uint2* seg = (uint2*)p;                     p += (size_t)E * 8;                  // 9.6 MB
    unsigned* bucket = (unsigned*)p;            p += (size_t)n * CAP * 4;            // 19.2 MB
    unsigned short* xb   = (unsigned short*)p;  p += (size_t)n * D * 2;              // 12.8 MB
    unsigned short* aggb = (unsigned short*)p;  p += (size_t)n * D * 2;              // 12.8 MB
    int* cnt = (int*)p;                         p += (size_t)n * 4;                  // 0.4 MB
    float* dis = (float*)p;                     p += (size_t)n * 4;                  // 0.4 MB
    float* stats = (float*)p;                   p += NREP * 128 * 4;
    int* cnt_gb = (int*)p;                      p += (size_t)G * NB * 4;             // 0.8 MB
    int* pos = (int*)p;                         p += (size_t)G * NB * 4;             // 0.8 MB
    int* gseg = (int*)p;                        p += ((size_t)G + 1) * 4;

    long long n16 = (long long)n * 16;

    k_prep<<<(unsigned)((n16 + 255) / 256), 256, 0, stream>>>(
        (const float4*)x, (ushort4*)xb, stats, n16);
    k_binA<<<NB, 256, 0, stream>>>(eidx + E, cnt_gb, G, E);
    k_scan<<<1, 256, 0, stream>>>(cnt_gb, pos, gseg, G, E);
    k_binB<<<NB, 256, 0, stream>>>(eidx, eattr, pos, seg, G, E);
    k_binC<<<G, 256, 0, stream>>>(seg, gseg, bucket, cnt, dis, n);
    k_gather<<<(n + 3) / 4, 256, 0, stream>>>(xb, bucket, cnt, dis, aggb, n);
    k_gemmstats<<<512, 256, 0, stream>>>(aggb, Wm, out, stats, n);
    k_norm<<<(unsigned)((n16 + 255) / 256), 256, 0, stream>>>(
        (float4*)out, stats, gamma, beta, n);
}

// Round 10
// 194.692 us; speedup vs baseline: 2.6673x; 2.6673x over previous
//
#include <hip/hip_runtime.h>

#define D 64
#define ALPHA 0.01f
#define EPS 1e-5f
#define NREP 8            // stats replica buffers
#define CAP 48            // bucket capacity; P(Poisson(12) >= 48) ~ 3e-15 per node
#define GSZ 128           // nodes per group (group = col >> 7)
#define GMAX 1024         // max groups supported (n <= 131072)
#define NB 256            // blocks for binA / binB

typedef __attribute__((ext_vector_type(8))) short short8;   // 8 bf16 = 4 VGPRs
typedef __attribute__((ext_vector_type(4))) float f32x4;

__device__ inline unsigned short f2bf(float f) {            // round-to-nearest-even
    unsigned u = __float_as_uint(f);
    u += 0x7fffu + ((u >> 16) & 1u);
    return (unsigned short)(u >> 16);
}
__device__ inline float bf2f(unsigned short h) { return __uint_as_float((unsigned)h << 16); }

// ---------------- prep: x->bf16, stats = 0 ----------------
__global__ void k_prep(const float4* __restrict__ x4, ushort4* __restrict__ xb4,
                       float* __restrict__ stats, long long n16) {
    long long i = (long long)blockIdx.x * blockDim.x + threadIdx.x;
    if (i < n16) {
        float4 v = x4[i];
        ushort4 r;
        r.x = f2bf(v.x); r.y = f2bf(v.y); r.z = f2bf(v.z); r.w = f2bf(v.w);
        xb4[i] = r;
    }
    if (i < NREP * 128) stats[i] = 0.0f;
}

// ---------------- binA: per-block LDS histogram over node-groups ----------------
__global__ __launch_bounds__(256) void k_binA(const int* __restrict__ col,
                                              int* __restrict__ cnt_gb, int G, int E) {
    __shared__ int h[GMAX];
    int b = blockIdx.x;
    for (int i = threadIdx.x; i < G; i += 256) h[i] = 0;
    __syncthreads();
    int chunk = (E + NB - 1) / NB;
    int e0 = b * chunk;
    int e1 = e0 + chunk; if (e1 > E) e1 = E;
    for (int e = e0 + threadIdx.x; e < e1; e += 256)
        atomicAdd(&h[col[e] >> 7], 1);
    __syncthreads();
    for (int i = threadIdx.x; i < G; i += 256)
        cnt_gb[i * NB + b] = h[i];          // [g][b] layout (group-major flat)
}

// ---------------- scanA: per-block sums over the flat (g,b) count array ----------------
__global__ __launch_bounds__(256) void k_scanA(const int* __restrict__ cnt_gb,
                                               int* __restrict__ bsum, int M) {
    __shared__ int ls[256];
    int base = blockIdx.x * 1024 + threadIdx.x * 4;
    int s = 0;
    if (base + 3 < M) {
        int4 v = *(const int4*)&cnt_gb[base];
        s = v.x + v.y + v.z + v.w;
    } else {
#pragma unroll
        for (int k = 0; k < 4; ++k) { int idx = base + k; if (idx < M) s += cnt_gb[idx]; }
    }
    ls[threadIdx.x] = s;
    __syncthreads();
    for (int off = 128; off > 0; off >>= 1) {
        if (threadIdx.x < off) ls[threadIdx.x] += ls[threadIdx.x + off];
        __syncthreads();
    }
    if (threadIdx.x == 0) bsum[blockIdx.x] = ls[0];
}

// ---------------- scanC: block base (local re-reduce of bsum) + local exclusive scan ----------------
// pos[f] = absolute start of (g = f>>8, b = f&255); gseg[g] at f%NB==0; gseg[G]=E
__global__ __launch_bounds__(256) void k_scanC(const int* __restrict__ cnt_gb,
                                               const int* __restrict__ bsum,
                                               int* __restrict__ pos,
                                               int* __restrict__ gseg, int M, int G, int E) {
    __shared__ int ls[256];
    int t = threadIdx.x;
    ls[t] = (t < blockIdx.x) ? bsum[t] : 0;   // #blocks <= 256
    __syncthreads();
    for (int off = 128; off > 0; off >>= 1) {
        if (t < off) ls[t] += ls[t + off];
        __syncthreads();
    }
    int base_total = ls[0];
    __syncthreads();
    int base = blockIdx.x * 1024 + t * 4;
    int v[4];
    int s = 0;
#pragma unroll
    for (int k = 0; k < 4; ++k) { int idx = base + k; v[k] = (idx < M) ? cnt_gb[idx] : 0; s += v[k]; }
    ls[t] = s;
    __syncthreads();
    int own = s;
    for (int off = 1; off < 256; off <<= 1) {
        int tv = (t >= off) ? ls[t - off] : 0;
        __syncthreads();
        ls[t] += tv;
        __syncthreads();
    }
    int excl = ls[t] - own + base_total;
#pragma unroll
    for (int k = 0; k < 4; ++k) {
        int idx = base + k;
        if (idx < M) {
            pos[idx] = excl;
            if ((idx & (NB - 1)) == 0) gseg[idx >> 8] = excl;
        }
        excl += v[k];
    }
    if (blockIdx.x == 0 && t == 0) gseg[G] = E;
}

// ---------------- binB: scatter edges into group segments (LDS cursors, no global atomics) ----
// entry: x = (wq 15b << 17) | row 17b  (== final bucket entry); y = col within group (7b)
__global__ __launch_bounds__(256) void k_binB(const int* __restrict__ eidx,
                                              const float* __restrict__ w,
                                              const int* __restrict__ pos,
                                              uint2* __restrict__ seg, int G, int E) {
    __shared__ int cursor[GMAX];
    int b = blockIdx.x;
    for (int g = threadIdx.x; g < G; g += 256) cursor[g] = pos[g * NB + b];
    __syncthreads();
    int chunk = (E + NB - 1) / NB;
    int e0 = b * chunk;
    int e1 = e0 + chunk; if (e1 > E) e1 = E;
    for (int e = e0 + threadIdx.x; e < e1; e += 256) {
        int row = eidx[e];
        int c = eidx[E + e];
        unsigned wq = (unsigned)(w[e] * 32767.0f + 0.5f);
        int slot = atomicAdd(&cursor[c >> 7], 1);
        seg[slot] = make_uint2((wq << 17) | (unsigned)row, (unsigned)(c & (GSZ - 1)));
    }
}

// ---------------- binC: per-group ranks (LDS) -> bucket, cnt, dis ----------------
__global__ __launch_bounds__(256) void k_binC(const uint2* __restrict__ seg,
                                              const int* __restrict__ gseg,
                                              unsigned* __restrict__ bucket,
                                              int* __restrict__ cnt,
                                              float* __restrict__ dis, int n) {
    __shared__ int cl[GSZ];
    __shared__ float ws[GSZ];
    int g = blockIdx.x;
    if (threadIdx.x < GSZ) { cl[threadIdx.x] = 0; ws[threadIdx.x] = 0.0f; }
    __syncthreads();
    int s0 = gseg[g], s1 = gseg[g + 1];
    for (int i = s0 + threadIdx.x; i < s1; i += 256) {
        uint2 ev = seg[i];
        int cig = (int)ev.y;
        int rank = atomicAdd(&cl[cig], 1);
        atomicAdd(&ws[cig], (float)(ev.x >> 17) * (1.0f / 32767.0f));
        int node = g * GSZ + cig;
        if (rank < CAP) bucket[(size_t)node * CAP + rank] = ev.x;
    }
    __syncthreads();
    if (threadIdx.x < GSZ) {
        int node = g * GSZ + threadIdx.x;
        if (node < n) {
            cnt[node] = cl[threadIdx.x];
            dis[node] = rsqrtf(1.0f + ws[threadIdx.x]);   // self-loop weight 1
        }
    }
}

// ---------------- gather: agg = A * x (one wave/node: 8 edge-slots x 8 lanes x 16B bf16) ----------------
__global__ __launch_bounds__(256) void k_gather(const unsigned short* __restrict__ xb,
                                                const unsigned* __restrict__ bucket,
                                                const int* __restrict__ cnt,
                                                const float* __restrict__ dis,
                                                unsigned short* __restrict__ aggb, int n) {
    int node = blockIdx.x * 4 + (threadIdx.x >> 6);
    if (node >= n) return;
    int lane = threadIdx.x & 63;
    int g = lane >> 3;      // edge slot 0..7
    int l = lane & 7;       // feature group (features 8l..8l+7)
    int c = cnt[node];
    if (c > CAP) c = CAP;
    float di = dis[node];
    float acc[8] = {0, 0, 0, 0, 0, 0, 0, 0};
    if (g == 0) {           // self-loop: norm = dis^2 = 1/deg
        float sl = di * di;
        short8 xv = *(const short8*)(xb + (size_t)node * 64 + l * 8);
#pragma unroll
        for (int k = 0; k < 8; ++k) acc[k] = bf2f((unsigned short)xv[k]) * sl;
    }
    for (int j = g; j < c; j += 8) {
        unsigned v = bucket[(size_t)node * CAP + j];
        int src = (int)(v & 0x1FFFFu);
        float we = (float)(v >> 17) * (1.0f / 32767.0f);
        float nrm = we * dis[src] * di;
        short8 xv = *(const short8*)(xb + (size_t)src * 64 + l * 8);
#pragma unroll
        for (int k = 0; k < 8; ++k) acc[k] += nrm * bf2f((unsigned short)xv[k]);
    }
#pragma unroll
    for (int off = 8; off <= 32; off <<= 1)
#pragma unroll
        for (int k = 0; k < 8; ++k) acc[k] += __shfl_xor(acc[k], off, 64);
    if (g == 0) {
        short8 r;
#pragma unroll
        for (int k = 0; k < 8; ++k) r[k] = (short)f2bf(acc[k]);
        *(short8*)(aggb + (size_t)node * 64 + l * 8) = r;
    }
}

// ---------------- out = agg @ W via MFMA 16x16x32 bf16, fused BN-stats ----------------
__global__ __launch_bounds__(256) void k_gemmstats(const unsigned short* __restrict__ aggb,
                                                   const float* __restrict__ Wm,
                                                   float* __restrict__ out,
                                                   float* __restrict__ stats, int n) {
    __shared__ unsigned short Wt[64 * 64];   // 8 KB, Wt[nn*64 + k]
    __shared__ float ssum[4][64], qsum[4][64];
    int tid = threadIdx.x;
    for (int i = tid; i < 4096; i += 256) {
        int k = i >> 6, nn = i & 63;
        Wt[nn * 64 + k] = f2bf(Wm[i]);
    }
    __syncthreads();
    int wv = tid >> 6;
    int lane = tid & 63;
    int l15 = lane & 15;
    int quad = lane >> 4;

    short8 bfrag[2][4];
#pragma unroll
    for (int h = 0; h < 2; ++h)
#pragma unroll
        for (int g = 0; g < 4; ++g)
            bfrag[h][g] = *(const short8*)&Wt[(g * 16 + l15) * 64 + h * 32 + quad * 8];

    float s[4] = {0, 0, 0, 0}, q[4] = {0, 0, 0, 0};
    int nwt = (n + 15) >> 4;   // wave-tiles
    for (int wt = blockIdx.x * 4 + wv; wt < nwt; wt += gridDim.x * 4) {
        int row0 = wt * 16;
        int arow = row0 + l15;
        if (arow >= n) arow = n - 1;           // clamp: loads stay in-bounds
        const unsigned short* ap = aggb + (size_t)arow * 64 + quad * 8;
        short8 a0 = *(const short8*)ap;
        short8 a1 = *(const short8*)(ap + 32);
        f32x4 acc[4] = {{0, 0, 0, 0}, {0, 0, 0, 0}, {0, 0, 0, 0}, {0, 0, 0, 0}};
#pragma unroll
        for (int g = 0; g < 4; ++g) {
            acc[g] = __builtin_amdgcn_mfma_f32_16x16x32_bf16(a0, bfrag[0][g], acc[g], 0, 0, 0);
            acc[g] = __builtin_amdgcn_mfma_f32_16x16x32_bf16(a1, bfrag[1][g], acc[g], 0, 0, 0);
        }
#pragma unroll
        for (int r = 0; r < 4; ++r) {
            int row = row0 + quad * 4 + r;
            if (row < n) {
                size_t base = (size_t)row * 64;
#pragma unroll
                for (int g = 0; g < 4; ++g) {
                    float v = acc[g][r];
                    out[base + g * 16 + l15] = v;
                    s[g] += v;
                    q[g] += v * v;
                }
            }
        }
    }
#pragma unroll
    for (int off = 16; off <= 32; off <<= 1) {
#pragma unroll
        for (int g = 0; g < 4; ++g) {
            s[g] += __shfl_xor(s[g], off, 64);
            q[g] += __shfl_xor(q[g], off, 64);
        }
    }
    if (quad == 0) {
#pragma unroll
        for (int g = 0; g < 4; ++g) { ssum[wv][g * 16 + l15] = s[g]; qsum[wv][g * 16 + l15] = q[g]; }
    }
    __syncthreads();
    float* st = stats + (blockIdx.x & (NREP - 1)) * 128;
    if (tid < 64)
        atomicAdd(&st[tid], ssum[0][tid] + ssum[1][tid] + ssum[2][tid] + ssum[3][tid]);
    else if (tid < 128) {
        int t = tid - 64;
        atomicAdd(&st[64 + t], qsum[0][t] + qsum[1][t] + qsum[2][t] + qsum[3][t]);
    }
}

// ---------------- batchnorm + leakyrelu, in place, float4 ----------------
__global__ __launch_bounds__(256) void k_norm(float4* __restrict__ out4,
                                              const float* __restrict__ stats,
                                              const float* __restrict__ gamma,
                                              const float* __restrict__ beta, int n) {
    __shared__ float scale[64], shift[64];
    if (threadIdx.x < 64) {
        float sm = 0.0f, qm = 0.0f;
#pragma unroll
        for (int r = 0; r < NREP; ++r) {
            sm += stats[r * 128 + threadIdx.x];
            qm += stats[r * 128 + 64 + threadIdx.x];
        }
        float inv_n = 1.0f / (float)n;
        float mean = sm * inv_n;
        float var = qm * inv_n - mean * mean;
        float sc = rsqrtf(var + EPS) * gamma[threadIdx.x];
        scale[threadIdx.x] = sc;
        shift[threadIdx.x] = beta[threadIdx.x] - mean * sc;
    }
    __syncthreads();
    long long idx = (long long)blockIdx.x * blockDim.x + threadIdx.x;
    if (idx < (long long)n * 16) {
        int l = (int)(idx & 15);
        float4 v = out4[idx];
        float4 r;
        float a, b2;
        a = scale[l * 4 + 0]; b2 = shift[l * 4 + 0]; r.x = v.x * a + b2; r.x = r.x >= 0.0f ? r.x : ALPHA * r.x;
        a = scale[l * 4 + 1]; b2 = shift[l * 4 + 1]; r.y = v.y * a + b2; r.y = r.y >= 0.0f ? r.y : ALPHA * r.y;
        a = scale[l * 4 + 2]; b2 = shift[l * 4 + 2]; r.z = v.z * a + b2; r.z = r.z >= 0.0f ? r.z : ALPHA * r.z;
        a = scale[l * 4 + 3]; b2 = shift[l * 4 + 3]; r.w = v.w * a + b2; r.w = r.w >= 0.0f ? r.w : ALPHA * r.w;
        out4[idx] = r;
    }
}

extern "C" void kernel_launch(void* const* d_in, const int* in_sizes, int n_in,
                              void* d_out, int out_size, void* d_ws, size_t ws_size,
                              hipStream_t stream) {
    const float* x     = (const float*)d_in[0];
    const int*   eidx  = (const int*)d_in[1];
    const float* eattr = (const float*)d_in[2];
    const float* Wm    = (const float*)d_in[3];
    // d_in[4] = b : constant per-feature shift, cancels exactly in BatchNorm — skipped
    const float* gamma = (const float*)d_in[5];
    const float* beta  = (const float*)d_in[6];
    float* out = (float*)d_out;

    int n = in_sizes[0] / D;      // 100000 < 2^17 (17-bit src packing, GMAX groups)
    int E = in_sizes[2];
    int G = (n + GSZ - 1) / GSZ;  // 782 node-groups
    int M = G * NB;               // 200192 (g,b) cells
    int nbs = (M + 1023) / 1024;  // 196 scan blocks (<= 256)

    // workspace layout (all sections 16B-aligned for n=100000, E=1.2M)
    char* p = (char*)d_ws;
    uint2* seg = (uint2*)p;                     p += (size_t)E * 8;                  // 9.6 MB
    unsigned* bucket = (unsigned*)p;            p += (size_t)n * CAP * 4;            // 19.2 MB
    unsigned short* xb   = (unsigned short*)p;  p += (size_t)n * D * 2;              // 12.8 MB
    unsigned short* aggb = (unsigned short*)p;  p += (size_t)n * D * 2;              // 12.8 MB
    int* cnt = (int*)p;                         p += (size_t)n * 4;                  // 0.4 MB
    float* dis = (float*)p;                     p += (size_t)n * 4;                  // 0.4 MB
    float* stats = (float*)p;                   p += NREP * 128 * 4;
    int* cnt_gb = (int*)p;                      p += (size_t)M * 4;                  // 0.8 MB
    int* pos = (int*)p;                         p += (size_t)M * 4;                  // 0.8 MB
    int* gseg = (int*)p;                        p += ((size_t)G + 1) * 4;
    int* bsum = (int*)p;                        p += 256 * 4;

    long long n16 = (long long)n * 16;

    k_prep<<<(unsigned)((n16 + 255) / 256), 256, 0, stream>>>(
        (const float4*)x, (ushort4*)xb, stats, n16);
    k_binA<<<NB, 256, 0, stream>>>(eidx + E, cnt_gb, G, E);
    k_scanA<<<nbs, 256, 0, stream>>>(cnt_gb, bsum, M);
    k_scanC<<<nbs, 256, 0, stream>>>(cnt_gb, bsum, pos, gseg, M, G, E);
    k_binB<<<NB, 256, 0, stream>>>(eidx, eattr, pos, seg, G, E);
    k_binC<<<G, 256, 0, stream>>>(seg, gseg, bucket, cnt, dis, n);
    k_gather<<<(n + 3) / 4, 256, 0, stream>>>(xb, bucket, cnt, dis, aggb, n);
    k_gemmstats<<<512, 256, 0, stream>>>(aggb, Wm, out, stats, n);
    k_norm<<<(unsigned)((n16 + 255) / 256), 256, 0, stream>>>(
        (float4*)out, stats, gamma, beta, n);
}

// Round 11
// 185.643 us; speedup vs baseline: 2.7973x; 1.0487x over previous
//
#include <hip/hip_runtime.h>

#define D 64
#define ALPHA 0.01f
#define EPS 1e-5f
#define NREP 8            // stats replica buffers
#define CAP 48            // bucket capacity; P(Poisson(12) >= 48) ~ 3e-15 per node
#define GSZ 128           // nodes per group (group = col >> 7)
#define GMAX 1024         // max groups supported (n <= 131072)
#define NB 256            // blocks for binA / binB

typedef __attribute__((ext_vector_type(8))) short short8;   // 8 bf16 = 4 VGPRs
typedef __attribute__((ext_vector_type(4))) float f32x4;

__device__ inline unsigned short f2bf(float f) {            // round-to-nearest-even
    unsigned u = __float_as_uint(f);
    u += 0x7fffu + ((u >> 16) & 1u);
    return (unsigned short)(u >> 16);
}
__device__ inline float bf2f(unsigned short h) { return __uint_as_float((unsigned)h << 16); }

// ---------------- prepA: blocks [0,NB) = binA histogram; rest = x->bf16 + stats=0 ----------------
__global__ __launch_bounds__(256) void k_prepA(const float4* __restrict__ x4,
                                               ushort4* __restrict__ xb4,
                                               float* __restrict__ stats,
                                               const int* __restrict__ col,
                                               int* __restrict__ cnt_gb,
                                               long long n16, int G, int E) {
    __shared__ int h[GMAX];
    if (blockIdx.x < NB) {
        int b = blockIdx.x;
        for (int i = threadIdx.x; i < G; i += 256) h[i] = 0;
        __syncthreads();
        int chunk = (E + NB - 1) / NB;
        int e0 = b * chunk;
        int e1 = e0 + chunk; if (e1 > E) e1 = E;
        for (int e = e0 + threadIdx.x; e < e1; e += 256)
            atomicAdd(&h[col[e] >> 7], 1);
        __syncthreads();
        for (int i = threadIdx.x; i < G; i += 256)
            cnt_gb[i * NB + b] = h[i];          // [g][b] layout
    } else {
        long long i = (long long)(blockIdx.x - NB) * 256 + threadIdx.x;
        if (i < n16) {
            float4 v = x4[i];
            ushort4 r;
            r.x = f2bf(v.x); r.y = f2bf(v.y); r.z = f2bf(v.z); r.w = f2bf(v.w);
            xb4[i] = r;
        }
        if (i < NREP * 128) stats[i] = 0.0f;
    }
}

// ---------------- scanA: per-block sums over the flat (g,b) count array ----------------
__global__ __launch_bounds__(256) void k_scanA(const int* __restrict__ cnt_gb,
                                               int* __restrict__ bsum, int M) {
    __shared__ int ls[256];
    int base = blockIdx.x * 1024 + threadIdx.x * 4;
    int s = 0;
    if (base + 3 < M) {
        int4 v = *(const int4*)&cnt_gb[base];
        s = v.x + v.y + v.z + v.w;
    } else {
#pragma unroll
        for (int k = 0; k < 4; ++k) { int idx = base + k; if (idx < M) s += cnt_gb[idx]; }
    }
    ls[threadIdx.x] = s;
    __syncthreads();
    for (int off = 128; off > 0; off >>= 1) {
        if (threadIdx.x < off) ls[threadIdx.x] += ls[threadIdx.x + off];
        __syncthreads();
    }
    if (threadIdx.x == 0) bsum[blockIdx.x] = ls[0];
}

// ---------------- scanC: block base (local re-reduce of bsum) + local exclusive scan ----------------
__global__ __launch_bounds__(256) void k_scanC(const int* __restrict__ cnt_gb,
                                               const int* __restrict__ bsum,
                                               int* __restrict__ pos,
                                               int* __restrict__ gseg, int M, int G, int E) {
    __shared__ int ls[256];
    int t = threadIdx.x;
    ls[t] = (t < blockIdx.x) ? bsum[t] : 0;   // #blocks <= 256
    __syncthreads();
    for (int off = 128; off > 0; off >>= 1) {
        if (t < off) ls[t] += ls[t + off];
        __syncthreads();
    }
    int base_total = ls[0];
    __syncthreads();
    int base = blockIdx.x * 1024 + t * 4;
    int v[4];
    int s = 0;
#pragma unroll
    for (int k = 0; k < 4; ++k) { int idx = base + k; v[k] = (idx < M) ? cnt_gb[idx] : 0; s += v[k]; }
    ls[t] = s;
    __syncthreads();
    int own = s;
    for (int off = 1; off < 256; off <<= 1) {
        int tv = (t >= off) ? ls[t - off] : 0;
        __syncthreads();
        ls[t] += tv;
        __syncthreads();
    }
    int excl = ls[t] - own + base_total;
#pragma unroll
    for (int k = 0; k < 4; ++k) {
        int idx = base + k;
        if (idx < M) {
            pos[idx] = excl;
            if ((idx & (NB - 1)) == 0) gseg[idx >> 8] = excl;
        }
        excl += v[k];
    }
    if (blockIdx.x == 0 && t == 0) gseg[G] = E;
}

// ---------------- binB: scatter edges into group segments (LDS cursors) ----------------
__global__ __launch_bounds__(256) void k_binB(const int* __restrict__ eidx,
                                              const float* __restrict__ w,
                                              const int* __restrict__ pos,
                                              uint2* __restrict__ seg, int G, int E) {
    __shared__ int cursor[GMAX];
    int b = blockIdx.x;
    for (int g = threadIdx.x; g < G; g += 256) cursor[g] = pos[g * NB + b];
    __syncthreads();
    int chunk = (E + NB - 1) / NB;
    int e0 = b * chunk;
    int e1 = e0 + chunk; if (e1 > E) e1 = E;
    for (int e = e0 + threadIdx.x; e < e1; e += 256) {
        int row = eidx[e];
        int c = eidx[E + e];
        unsigned wq = (unsigned)(w[e] * 32767.0f + 0.5f);
        int slot = atomicAdd(&cursor[c >> 7], 1);
        seg[slot] = make_uint2((wq << 17) | (unsigned)row, (unsigned)(c & (GSZ - 1)));
    }
}

// ---------------- binC: per-group ranks (LDS) -> bucket, cnt, dis, dis_s ----------------
__global__ __launch_bounds__(256) void k_binC(const uint2* __restrict__ seg,
                                              const int* __restrict__ gseg,
                                              unsigned* __restrict__ bucket,
                                              int* __restrict__ cnt,
                                              float* __restrict__ dis,
                                              float* __restrict__ dis_s, int n) {
    __shared__ int cl[GSZ];
    __shared__ float ws[GSZ];
    int g = blockIdx.x;
    if (threadIdx.x < GSZ) { cl[threadIdx.x] = 0; ws[threadIdx.x] = 0.0f; }
    __syncthreads();
    int s0 = gseg[g], s1 = gseg[g + 1];
    for (int i = s0 + threadIdx.x; i < s1; i += 256) {
        uint2 ev = seg[i];
        int cig = (int)ev.y;
        int rank = atomicAdd(&cl[cig], 1);
        atomicAdd(&ws[cig], (float)(ev.x >> 17) * (1.0f / 32767.0f));
        int node = g * GSZ + cig;
        if (rank < CAP) bucket[(size_t)node * CAP + rank] = ev.x;
    }
    __syncthreads();
    if (threadIdx.x < GSZ) {
        int node = g * GSZ + threadIdx.x;
        if (node < n) {
            cnt[node] = cl[threadIdx.x];
            float d = rsqrtf(1.0f + ws[threadIdx.x]);   // self-loop weight 1
            dis[node] = d;
            dis_s[node] = d * (1.0f / 32767.0f);        // dequant constant folded in
        }
    }
}

// ---------------- gather v2: di factored out, unroll-2 pipeline per edge-slot ----------------
__global__ __launch_bounds__(256) void k_gather(const unsigned short* __restrict__ xb,
                                                const unsigned* __restrict__ bucket,
                                                const int* __restrict__ cnt,
                                                const float* __restrict__ dis,
                                                const float* __restrict__ dis_s,
                                                unsigned short* __restrict__ aggb, int n) {
    int node = blockIdx.x * 4 + (threadIdx.x >> 6);
    if (node >= n) return;
    int lane = threadIdx.x & 63;
    int g = lane >> 3;      // edge slot 0..7
    int l = lane & 7;       // feature group (features 8l..8l+7)
    int c = cnt[node];
    if (c > CAP) c = CAP;
    float di = dis[node];
    float acc[8] = {0, 0, 0, 0, 0, 0, 0, 0};
    if (g == 0) {           // self-loop: di*x now, *di at epilogue -> di^2 = 1/deg
        short8 xv = *(const short8*)(xb + ((size_t)node << 6) + l * 8);
#pragma unroll
        for (int k = 0; k < 8; ++k) acc[k] = bf2f((unsigned short)xv[k]) * di;
    }
    const unsigned* bkt = bucket + (size_t)node * CAP;
    int j0 = g, j1 = g + 8;
    unsigned v0 = (j0 < c) ? bkt[j0] : 0u;   // wq=0 => zero contribution, safe
    unsigned v1 = (j1 < c) ? bkt[j1] : 0u;
    while (j0 < c) {
        int p0 = j0 + 16, p1 = j1 + 16;
        unsigned w0 = (p0 < c) ? bkt[p0] : 0u;
        unsigned w1 = (p1 < c) ? bkt[p1] : 0u;
        int s0 = (int)(v0 & 0x1FFFFu);
        int s1 = (int)(v1 & 0x1FFFFu);
        float nr0 = (float)(v0 >> 17) * dis_s[s0];   // = w * dis[src]
        float nr1 = (float)(v1 >> 17) * dis_s[s1];
        short8 x0 = *(const short8*)(xb + ((size_t)s0 << 6) + l * 8);
        short8 x1 = *(const short8*)(xb + ((size_t)s1 << 6) + l * 8);
#pragma unroll
        for (int k = 0; k < 8; ++k) acc[k] += nr0 * bf2f((unsigned short)x0[k]);
#pragma unroll
        for (int k = 0; k < 8; ++k) acc[k] += nr1 * bf2f((unsigned short)x1[k]);
        v0 = w0; v1 = w1; j0 = p0; j1 = p1;
    }
#pragma unroll
    for (int off = 8; off <= 32; off <<= 1)
#pragma unroll
        for (int k = 0; k < 8; ++k) acc[k] += __shfl_xor(acc[k], off, 64);
    if (g == 0) {
        short8 r;
#pragma unroll
        for (int k = 0; k < 8; ++k) r[k] = (short)f2bf(acc[k] * di);
        *(short8*)(aggb + ((size_t)node << 6) + l * 8) = r;
    }
}

// ---------------- out = agg @ W via MFMA 16x16x32 bf16, fused BN-stats ----------------
__global__ __launch_bounds__(256) void k_gemmstats(const unsigned short* __restrict__ aggb,
                                                   const float* __restrict__ Wm,
                                                   float* __restrict__ out,
                                                   float* __restrict__ stats, int n) {
    __shared__ unsigned short Wt[64 * 64];   // 8 KB, Wt[nn*64 + k]
    __shared__ float ssum[4][64], qsum[4][64];
    int tid = threadIdx.x;
    for (int i = tid; i < 4096; i += 256) {
        int k = i >> 6, nn = i & 63;
        Wt[nn * 64 + k] = f2bf(Wm[i]);
    }
    __syncthreads();
    int wv = tid >> 6;
    int lane = tid & 63;
    int l15 = lane & 15;
    int quad = lane >> 4;

    short8 bfrag[2][4];
#pragma unroll
    for (int h = 0; h < 2; ++h)
#pragma unroll
        for (int g = 0; g < 4; ++g)
            bfrag[h][g] = *(const short8*)&Wt[(g * 16 + l15) * 64 + h * 32 + quad * 8];

    float s[4] = {0, 0, 0, 0}, q[4] = {0, 0, 0, 0};
    int nwt = (n + 15) >> 4;   // wave-tiles
    for (int wt = blockIdx.x * 4 + wv; wt < nwt; wt += gridDim.x * 4) {
        int row0 = wt * 16;
        int arow = row0 + l15;
        if (arow >= n) arow = n - 1;           // clamp: loads stay in-bounds
        const unsigned short* ap = aggb + (size_t)arow * 64 + quad * 8;
        short8 a0 = *(const short8*)ap;
        short8 a1 = *(const short8*)(ap + 32);
        f32x4 acc[4] = {{0, 0, 0, 0}, {0, 0, 0, 0}, {0, 0, 0, 0}, {0, 0, 0, 0}};
#pragma unroll
        for (int g = 0; g < 4; ++g) {
            acc[g] = __builtin_amdgcn_mfma_f32_16x16x32_bf16(a0, bfrag[0][g], acc[g], 0, 0, 0);
            acc[g] = __builtin_amdgcn_mfma_f32_16x16x32_bf16(a1, bfrag[1][g], acc[g], 0, 0, 0);
        }
#pragma unroll
        for (int r = 0; r < 4; ++r) {
            int row = row0 + quad * 4 + r;
            if (row < n) {
                size_t base = (size_t)row * 64;
#pragma unroll
                for (int g = 0; g < 4; ++g) {
                    float v = acc[g][r];
                    out[base + g * 16 + l15] = v;
                    s[g] += v;
                    q[g] += v * v;
                }
            }
        }
    }
#pragma unroll
    for (int off = 16; off <= 32; off <<= 1) {
#pragma unroll
        for (int g = 0; g < 4; ++g) {
            s[g] += __shfl_xor(s[g], off, 64);
            q[g] += __shfl_xor(q[g], off, 64);
        }
    }
    if (quad == 0) {
#pragma unroll
        for (int g = 0; g < 4; ++g) { ssum[wv][g * 16 + l15] = s[g]; qsum[wv][g * 16 + l15] = q[g]; }
    }
    __syncthreads();
    float* st = stats + (blockIdx.x & (NREP - 1)) * 128;
    if (tid < 64)
        atomicAdd(&st[tid], ssum[0][tid] + ssum[1][tid] + ssum[2][tid] + ssum[3][tid]);
    else if (tid < 128) {
        int t = tid - 64;
        atomicAdd(&st[64 + t], qsum[0][t] + qsum[1][t] + qsum[2][t] + qsum[3][t]);
    }
}

// ---------------- batchnorm + leakyrelu, in place, float4 ----------------
__global__ __launch_bounds__(256) void k_norm(float4* __restrict__ out4,
                                              const float* __restrict__ stats,
                                              const float* __restrict__ gamma,
                                              const float* __restrict__ beta, int n) {
    __shared__ float scale[64], shift[64];
    if (threadIdx.x < 64) {
        float sm = 0.0f, qm = 0.0f;
#pragma unroll
        for (int r = 0; r < NREP; ++r) {
            sm += stats[r * 128 + threadIdx.x];
            qm += stats[r * 128 + 64 + threadIdx.x];
        }
        float inv_n = 1.0f / (float)n;
        float mean = sm * inv_n;
        float var = qm * inv_n - mean * mean;
        float sc = rsqrtf(var + EPS) * gamma[threadIdx.x];
        scale[threadIdx.x] = sc;
        shift[threadIdx.x] = beta[threadIdx.x] - mean * sc;
    }
    __syncthreads();
    long long idx = (long long)blockIdx.x * blockDim.x + threadIdx.x;
    if (idx < (long long)n * 16) {
        int l = (int)(idx & 15);
        float4 v = out4[idx];
        float4 r;
        float a, b2;
        a = scale[l * 4 + 0]; b2 = shift[l * 4 + 0]; r.x = v.x * a + b2; r.x = r.x >= 0.0f ? r.x : ALPHA * r.x;
        a = scale[l * 4 + 1]; b2 = shift[l * 4 + 1]; r.y = v.y * a + b2; r.y = r.y >= 0.0f ? r.y : ALPHA * r.y;
        a = scale[l * 4 + 2]; b2 = shift[l * 4 + 2]; r.z = v.z * a + b2; r.z = r.z >= 0.0f ? r.z : ALPHA * r.z;
        a = scale[l * 4 + 3]; b2 = shift[l * 4 + 3]; r.w = v.w * a + b2; r.w = r.w >= 0.0f ? r.w : ALPHA * r.w;
        out4[idx] = r;
    }
}

extern "C" void kernel_launch(void* const* d_in, const int* in_sizes, int n_in,
                              void* d_out, int out_size, void* d_ws, size_t ws_size,
                              hipStream_t stream) {
    const float* x     = (const float*)d_in[0];
    const int*   eidx  = (const int*)d_in[1];
    const float* eattr = (const float*)d_in[2];
    const float* Wm    = (const float*)d_in[3];
    // d_in[4] = b : constant per-feature shift, cancels exactly in BatchNorm — skipped
    const float* gamma = (const float*)d_in[5];
    const float* beta  = (const float*)d_in[6];
    float* out = (float*)d_out;

    int n = in_sizes[0] / D;      // 100000 < 2^17 (17-bit src packing, GMAX groups)
    int E = in_sizes[2];
    int G = (n + GSZ - 1) / GSZ;  // 782 node-groups
    int M = G * NB;               // 200192 (g,b) cells
    int nbs = (M + 1023) / 1024;  // 196 scan blocks (<= 256)

    // workspace layout (all sections 16B-aligned for n=100000, E=1.2M)
    char* p = (char*)d_ws;
    uint2* seg = (uint2*)p;                     p += (size_t)E * 8;                  // 9.6 MB
    unsigned* bucket = (unsigned*)p;            p += (size_t)n * CAP * 4;            // 19.2 MB
    unsigned short* xb   = (unsigned short*)p;  p += (size_t)n * D * 2;              // 12.8 MB
    unsigned short* aggb = (unsigned short*)p;  p += (size_t)n * D * 2;              // 12.8 MB
    int* cnt = (int*)p;                         p += (size_t)n * 4;                  // 0.4 MB
    float* dis = (float*)p;                     p += (size_t)n * 4;                  // 0.4 MB
    float* dis_s = (float*)p;                   p += (size_t)n * 4;                  // 0.4 MB
    float* stats = (float*)p;                   p += NREP * 128 * 4;
    int* cnt_gb = (int*)p;                      p += (size_t)M * 4;                  // 0.8 MB
    int* pos = (int*)p;                         p += (size_t)M * 4;                  // 0.8 MB
    int* gseg = (int*)p;                        p += ((size_t)G + 1) * 4;
    int* bsum = (int*)p;                        p += 256 * 4;

    long long n16 = (long long)n * 16;
    unsigned prep_blocks = (unsigned)((n16 + 255) / 256);

    k_prepA<<<NB + prep_blocks, 256, 0, stream>>>(
        (const float4*)x, (ushort4*)xb, stats, eidx + E, cnt_gb, n16, G, E);
    k_scanA<<<nbs, 256, 0, stream>>>(cnt_gb, bsum, M);
    k_scanC<<<nbs, 256, 0, stream>>>(cnt_gb, bsum, pos, gseg, M, G, E);
    k_binB<<<NB, 256, 0, stream>>>(eidx, eattr, pos, seg, G, E);
    k_binC<<<G, 256, 0, stream>>>(seg, gseg, bucket, cnt, dis, dis_s, n);
    k_gather<<<(n + 3) / 4, 256, 0, stream>>>(xb, bucket, cnt, dis, dis_s, aggb, n);
    k_gemmstats<<<1024, 256, 0, stream>>>(aggb, Wm, out, stats, n);
    k_norm<<<(unsigned)((n16 + 255) / 256), 256, 0, stream>>>(
        (float4*)out, stats, gamma, beta, n);
}